// Round 2
// baseline (216.001 us; speedup 1.0000x reference)
//
#include <hip/hip_runtime.h>

#define NG   1024
#define NCLS 18
#define HH   100
#define WW   100
#define DD   8
#define PTOT (HH*WW*DD)

// ---------------------------------------------------------------------------
// Kernel 1: per-gaussian precompute.
// cov = R diag(s^2) R^T  =>  A = inv(cov) = R diag(1/s^2) R^T (R orthonormal).
// Layout in ws (floats):
//   g0[n*8]  = {mu.x, mu.y, mu.z, 3sx, 3sy, 3sz, 0, 0}      (mask data)
//   g1[n*8]  = {A00, A01, A02, A11, A12, A22, opa, 0}        (body data)
//   gf[n*20] = {f0..f16, 0,0,0}                              (features)
// ---------------------------------------------------------------------------
__global__ __launch_bounds__(256) void gv_pre(
    const float* __restrict__ means, const float* __restrict__ opac,
    const float* __restrict__ scales, const float* __restrict__ rots,
    const float* __restrict__ feats,
    float* __restrict__ g0, float* __restrict__ g1, float* __restrict__ gf)
{
    int n = blockIdx.x * blockDim.x + threadIdx.x;
    if (n >= NG) return;

    float qw = rots[n*4+0], qx = rots[n*4+1], qy = rots[n*4+2], qz = rots[n*4+3];
    float inv = rsqrtf(qw*qw + qx*qx + qy*qy + qz*qz);
    qw *= inv; qx *= inv; qy *= inv; qz *= inv;

    float R00 = 1.f - 2.f*(qy*qy + qz*qz), R01 = 2.f*(qx*qy - qw*qz), R02 = 2.f*(qx*qz + qw*qy);
    float R10 = 2.f*(qx*qy + qw*qz), R11 = 1.f - 2.f*(qx*qx + qz*qz), R12 = 2.f*(qy*qz - qw*qx);
    float R20 = 2.f*(qx*qz - qw*qy), R21 = 2.f*(qy*qz + qw*qx), R22 = 1.f - 2.f*(qx*qx + qy*qy);

    float sx = scales[n*3+0], sy = scales[n*3+1], sz = scales[n*3+2];
    float ix = 1.f/(sx*sx), iy = 1.f/(sy*sy), iz = 1.f/(sz*sz);

    float A00 = R00*R00*ix + R01*R01*iy + R02*R02*iz;
    float A01 = R00*R10*ix + R01*R11*iy + R02*R12*iz;
    float A02 = R00*R20*ix + R01*R21*iy + R02*R22*iz;
    float A11 = R10*R10*ix + R11*R11*iy + R12*R12*iz;
    float A12 = R10*R20*ix + R11*R21*iy + R12*R22*iz;
    float A22 = R20*R20*ix + R21*R21*iy + R22*R22*iz;

    float* p0 = g0 + n*8;
    p0[0] = means[n*3+0]; p0[1] = means[n*3+1]; p0[2] = means[n*3+2];
    p0[3] = 3.f*sx; p0[4] = 3.f*sy; p0[5] = 3.f*sz; p0[6] = 0.f; p0[7] = 0.f;

    float* p1 = g1 + n*8;
    p1[0] = A00; p1[1] = A01; p1[2] = A02; p1[3] = A11; p1[4] = A12; p1[5] = A22;
    p1[6] = opac[n]; p1[7] = 0.f;

    float* pf = gf + n*20;
    #pragma unroll
    for (int c = 0; c < 17; ++c) pf[c] = feats[n*17 + c];
    pf[17] = 0.f; pf[18] = 0.f; pf[19] = 0.f;
}

// ---------------------------------------------------------------------------
// Kernel 2: one thread per voxel; scan all gaussians with AABB early-out.
// Empty gaussian (index NG in the reference) is closed-form: diag cov with
// rng=(80,80,6.4), center=(0,0,2.2), opa=1, feeds only class 17 scaled by
// empty_scalar. Its mask radius (3*rng) always covers the grid.
// ---------------------------------------------------------------------------
__global__ __launch_bounds__(256) void gv_main(
    const float* __restrict__ g0, const float* __restrict__ g1,
    const float* __restrict__ gf, const float* __restrict__ empty_scalar,
    float* __restrict__ out)
{
    int p = blockIdx.x * 256 + threadIdx.x;
    if (p >= PTOT) return;

    int k  = p & 7;      // D = 8
    int ij = p >> 3;     // i*100 + j
    int i  = ij / 100;
    int j  = ij - i*100;

    float x = (i + 0.5f) * 0.8f - 40.f;
    float y = (j + 0.5f) * 0.8f - 40.f;
    float z = (k + 0.5f) * 0.8f - 1.f;

    float acc[17];
    #pragma unroll
    for (int c = 0; c < 17; ++c) acc[c] = 0.f;

    for (int n = 0; n < NG; ++n) {
        const float* a = g0 + n*8;       // wave-uniform address -> s_load
        float dx = x - a[0], dy = y - a[1], dz = z - a[2];
        if (fabsf(dx) <= a[3] && fabsf(dy) <= a[4] && fabsf(dz) <= a[5]) {
            const float* b = g1 + n*8;
            float maha = dx*(dx*b[0] + 2.f*(dy*b[1] + dz*b[2]))
                       + dy*(dy*b[3] + 2.f*dz*b[4])
                       + dz*dz*b[5];
            float w = b[6] * __expf(-0.5f * maha);
            const float* f = gf + n*20;
            #pragma unroll
            for (int c = 0; c < 17; ++c) acc[c] = fmaf(w, f[c], acc[c]);
        }
    }

    // empty gaussian: A = diag(1/6400, 1/6400, 1/40.96), mu = (0,0,2.2)
    float dz0 = z - 2.2f;
    float me  = x*x*(1.f/6400.f) + y*y*(1.f/6400.f) + dz0*dz0*(1.f/40.96f);
    float w17 = empty_scalar[0] * __expf(-0.5f * me);

    out[p] = 0.f;                        // grid_density is all zeros
    float* o = out + PTOT + p*NCLS;
    #pragma unroll
    for (int c = 0; c < 17; ++c) o[c] = acc[c];
    o[17] = w17;
}

extern "C" void kernel_launch(void* const* d_in, const int* in_sizes, int n_in,
                              void* d_out, int out_size, void* d_ws, size_t ws_size,
                              hipStream_t stream) {
    const float* means  = (const float*)d_in[0];
    const float* opac   = (const float*)d_in[1];
    const float* scales = (const float*)d_in[2];
    const float* rots   = (const float*)d_in[3];
    const float* feats  = (const float*)d_in[4];
    const float* es     = (const float*)d_in[5];

    float* ws = (float*)d_ws;
    float* g0 = ws;              // NG*8 floats
    float* g1 = ws + NG*8;       // NG*8 floats
    float* gf = ws + NG*16;      // NG*20 floats
    float* out = (float*)d_out;

    gv_pre<<<(NG + 255) / 256, 256, 0, stream>>>(means, opac, scales, rots, feats, g0, g1, gf);
    gv_main<<<(PTOT + 255) / 256, 256, 0, stream>>>(g0, g1, gf, es, out);
}

// Round 3
// 74.853 us; speedup vs baseline: 2.8857x; 2.8857x over previous
//
#include <hip/hip_runtime.h>

#define NG   1024
#define NCLS 18
#define HH   100
#define WW   100
#define DD   8
#define PTOT (HH*WW*DD)
#define TI   4     // voxels per block in i
#define TJ   8     // voxels per block in j (k covers all 8)
#define CH   128   // survivors derived per chunk

// One fused kernel. Per block: cull 1024 gaussians against the block's
// voxel-center AABB (expected ~20 survivors), compute survivors' derived
// data {mu, 3s, A = R diag(s^-2) R^T, opa, feats} into LDS, then each
// thread (1 voxel) loops survivors with LDS-broadcast reads.
// Empty gaussian (reference index NG) is closed-form in the epilogue.
__global__ __launch_bounds__(256) void gv_fused(
    const float* __restrict__ means, const float* __restrict__ opac,
    const float* __restrict__ scales, const float* __restrict__ rots,
    const float* __restrict__ feats, const float* __restrict__ es,
    float* __restrict__ out)
{
    __shared__ int   s_idx[NG];       // survivor indices (worst case all)
    __shared__ float s_g[CH][32];     // derived data, 32-float stride
    __shared__ int   s_cnt;

    const int tid = threadIdx.x;
    const int i0  = blockIdx.x * TI;
    const int j0  = blockIdx.y * TJ;
    const int jmax = min(j0 + TJ - 1, WW - 1);

    // AABB of this block's voxel CENTERS
    const float xlo = (i0 + 0.5f) * 0.8f - 40.f;
    const float xhi = (i0 + TI - 1 + 0.5f) * 0.8f - 40.f;
    const float ylo = (j0 + 0.5f) * 0.8f - 40.f;
    const float yhi = (jmax + 0.5f) * 0.8f - 40.f;
    const float zlo = 0.5f * 0.8f - 1.f;            // -0.6
    const float zhi = (DD - 1 + 0.5f) * 0.8f - 1.f; //  5.0

    if (tid == 0) s_cnt = 0;
    __syncthreads();

    // ---- Phase 1: cull (4 gaussians per thread, coalesced) ----
    #pragma unroll
    for (int n = tid; n < NG; n += 256) {
        float mx = means[n*3+0], my = means[n*3+1], mz = means[n*3+2];
        float rx = 3.f*scales[n*3+0], ry = 3.f*scales[n*3+1], rz = 3.f*scales[n*3+2];
        bool ov = (mx - rx <= xhi) & (mx + rx >= xlo)
                & (my - ry <= yhi) & (my + ry >= ylo)
                & (mz - rz <= zhi) & (mz + rz >= zlo);
        if (ov) s_idx[atomicAdd(&s_cnt, 1)] = n;
    }
    __syncthreads();
    const int ns = s_cnt;

    // this thread's voxel
    const int dk = tid & 7, dj = (tid >> 3) & 7, di = tid >> 6;
    const int i = i0 + di, j = j0 + dj, k = dk;
    const bool valid = (j < WW);
    const float x = (i + 0.5f) * 0.8f - 40.f;
    const float y = (j + 0.5f) * 0.8f - 40.f;
    const float z = (k + 0.5f) * 0.8f - 1.f;

    float acc[17];
    #pragma unroll
    for (int c = 0; c < 17; ++c) acc[c] = 0.f;

    // ---- Phase 2: chunked derived-data compute + accumulate ----
    for (int base = 0; base < ns; base += CH) {
        const int m = min(CH, ns - base);
        __syncthreads();                       // protect s_g reuse
        if (tid < m) {
            int n = s_idx[base + tid];
            float qw = rots[n*4+0], qx = rots[n*4+1], qy = rots[n*4+2], qz = rots[n*4+3];
            float inv = rsqrtf(qw*qw + qx*qx + qy*qy + qz*qz);
            qw *= inv; qx *= inv; qy *= inv; qz *= inv;
            float R00 = 1.f - 2.f*(qy*qy + qz*qz), R01 = 2.f*(qx*qy - qw*qz), R02 = 2.f*(qx*qz + qw*qy);
            float R10 = 2.f*(qx*qy + qw*qz), R11 = 1.f - 2.f*(qx*qx + qz*qz), R12 = 2.f*(qy*qz - qw*qx);
            float R20 = 2.f*(qx*qz - qw*qy), R21 = 2.f*(qy*qz + qw*qx), R22 = 1.f - 2.f*(qx*qx + qy*qy);
            float sx = scales[n*3+0], sy = scales[n*3+1], sz = scales[n*3+2];
            float ix = 1.f/(sx*sx), iy = 1.f/(sy*sy), iz = 1.f/(sz*sz);
            float* g = s_g[tid];
            g[0] = means[n*3+0]; g[1] = means[n*3+1]; g[2] = means[n*3+2];
            g[3] = 3.f*sx; g[4] = 3.f*sy; g[5] = 3.f*sz;
            g[6]  = R00*R00*ix + R01*R01*iy + R02*R02*iz;
            g[7]  = R00*R10*ix + R01*R11*iy + R02*R12*iz;
            g[8]  = R00*R20*ix + R01*R21*iy + R02*R22*iz;
            g[9]  = R10*R10*ix + R11*R11*iy + R12*R12*iz;
            g[10] = R10*R20*ix + R11*R21*iy + R12*R22*iz;
            g[11] = R20*R20*ix + R21*R21*iy + R22*R22*iz;
            g[12] = opac[n];
            #pragma unroll
            for (int c = 0; c < 17; ++c) g[13+c] = feats[n*17+c];
        }
        __syncthreads();
        if (valid) {
            for (int t = 0; t < m; ++t) {
                const float* g = s_g[t];           // all lanes same addr -> broadcast
                float dx = x - g[0], dy = y - g[1], dz = z - g[2];
                if (fabsf(dx) <= g[3] && fabsf(dy) <= g[4] && fabsf(dz) <= g[5]) {
                    float maha = dx*(dx*g[6] + 2.f*(dy*g[7] + dz*g[8]))
                               + dy*(dy*g[9] + 2.f*dz*g[10])
                               + dz*dz*g[11];
                    float w = g[12] * __expf(-0.5f * maha);
                    #pragma unroll
                    for (int c = 0; c < 17; ++c) acc[c] = fmaf(w, g[13+c], acc[c]);
                }
            }
        }
    }

    // ---- Epilogue: empty gaussian + stores ----
    if (valid) {
        int p = (i*WW + j)*DD + k;
        float dz0 = z - 2.2f;
        float me  = x*x*(1.f/6400.f) + y*y*(1.f/6400.f) + dz0*dz0*(1.f/40.96f);
        float w17 = es[0] * __expf(-0.5f * me);
        out[p] = 0.f;                              // grid_density
        float* o = out + PTOT + p*NCLS;
        #pragma unroll
        for (int c = 0; c < 17; ++c) o[c] = acc[c];
        o[17] = w17;
    }
}

extern "C" void kernel_launch(void* const* d_in, const int* in_sizes, int n_in,
                              void* d_out, int out_size, void* d_ws, size_t ws_size,
                              hipStream_t stream) {
    const float* means  = (const float*)d_in[0];
    const float* opac   = (const float*)d_in[1];
    const float* scales = (const float*)d_in[2];
    const float* rots   = (const float*)d_in[3];
    const float* feats  = (const float*)d_in[4];
    const float* es     = (const float*)d_in[5];
    float* out = (float*)d_out;

    dim3 grid((HH + TI - 1) / TI, (WW + TJ - 1) / TJ);  // 25 x 13
    gv_fused<<<grid, 256, 0, stream>>>(means, opac, scales, rots, feats, es, out);
}